// Round 1
// baseline (313.086 us; speedup 1.0000x reference)
//
#include <hip/hip_runtime.h>

#define NTH 256

// Bijective LDS word-index swizzle: XOR bits [8:6] into bank-group bits [4:2].
// Constant over any 4-aligned float4 block -> preserves b128 contiguity.
__device__ __forceinline__ int swz(int f) { return f ^ (((f >> 6) & 7) << 2); }

__device__ __forceinline__ void fma4(float4& a, const float4& v, float s) {
  a.x = fmaf(v.x, s, a.x);
  a.y = fmaf(v.y, s, a.y);
  a.z = fmaf(v.z, s, a.z);
  a.w = fmaf(v.w, s, a.w);
}

// One column-absorption step:
//   out[((w*D+d)*R+r)*V + v] = sum_{h<H,u<U} in[((w*H+h)*U+u)*V + v] * T[u,d,h,r]
// T staged in LDS as sT[((h*U+u)*D+d)*R + r].
template<int U, int D, int H, int R>
__device__ __forceinline__ void absorb(const float* __restrict__ tens, int sbase,
                                       const float* __restrict__ sin_,
                                       float* __restrict__ sout,
                                       float* __restrict__ sT,
                                       int wcnt, int V, int tid)
{
  constexpr int TSZ = U * D * H * R;
  if (tid < TSZ) {
    int t = tid;
    int r = t % R; t /= R;
    int d = t % D; t /= D;
    int u = t % U; t /= U;
    int h = t;
    // tensors[i][j][u][d][l][r][p]: strides 512,512,128,32,8,2,1
    sT[tid] = tens[sbase + u * 128 + d * 32 + h * 8 + r * 2];
  }
  __syncthreads();

  const int lane = tid & 63, wave = tid >> 6;
  int g, start, stride;
  if (D == 4) { g = wave; start = lane; stride = 64; }   // wave owns d = g
  else        { g = 0;    start = tid;  stride = NTH; }

  if (V >= 4) {
    const int Vq  = V >> 2;
    const int lvq = 31 - __clz(Vq);
    // T fragment for this wave's d: float4 over r
    float4 t4[H][U];
#pragma unroll
    for (int h = 0; h < H; ++h)
#pragma unroll
      for (int u = 0; u < U; ++u) {
        if (R == 4) {
          t4[h][u] = *(const float4*)&sT[((h * U + u) * D + g) * 4];
        } else {
          float s0 = sT[(h * U + u) * D + g];
          t4[h][u] = make_float4(s0, 0.f, 0.f, 0.f);
        }
      }
    const int nvec = wcnt * Vq;
    for (int s = start; s < nvec; s += stride) {
      const int vb = s & (Vq - 1);
      const int w  = s >> lvq;
      const int ib = w * (H * U) * V + (vb << 2);
      float4 iv[H][U];
#pragma unroll
      for (int h = 0; h < H; ++h)
#pragma unroll
        for (int u = 0; u < U; ++u)
          iv[h][u] = *(const float4*)&sin_[swz(ib + (h * U + u) * V)];
      float4 acc[R];
#pragma unroll
      for (int r = 0; r < R; ++r) acc[r] = make_float4(0.f, 0.f, 0.f, 0.f);
#pragma unroll
      for (int h = 0; h < H; ++h)
#pragma unroll
        for (int u = 0; u < U; ++u) {
          const float4 t = t4[h][u];
          const float4 a = iv[h][u];
          fma4(acc[0], a, t.x);
          if (R == 4) {
            fma4(acc[1], a, t.y);
            fma4(acc[2], a, t.z);
            fma4(acc[3], a, t.w);
          }
        }
      const int ob = (w * D + g) * R * V + (vb << 2);
#pragma unroll
      for (int r = 0; r < R; ++r)
        *(float4*)&sout[swz(ob + r * V)] = acc[r];
    }
  } else {
    // V == 1 path: in is contiguous over (h,u) for fixed w.
    const int nout = wcnt * R;
    for (int s = start; s < nout; s += stride) {
      const int r = (R == 4) ? (s & 3) : 0;
      const int w = (R == 4) ? (s >> 2) : s;
      float acc = 0.f;
#pragma unroll
      for (int h = 0; h < H; ++h) {
        if (U == 4) {
          const float4 iv = *(const float4*)&sin_[swz((w * H + h) * 4)];
          acc = fmaf(iv.x, sT[((h * 4 + 0) * D + g) * R + r], acc);
          acc = fmaf(iv.y, sT[((h * 4 + 1) * D + g) * R + r], acc);
          acc = fmaf(iv.z, sT[((h * 4 + 2) * D + g) * R + r], acc);
          acc = fmaf(iv.w, sT[((h * 4 + 3) * D + g) * R + r], acc);
        } else {
          acc = fmaf(sin_[swz(w * H + h)], sT[(h * D + g) * R + r], acc);
        }
      }
      sout[swz((w * D + g) * R + r)] = acc;
    }
  }
  __syncthreads();
}

__global__ __launch_bounds__(NTH, 1)
void tn_kernel(const float* __restrict__ tensors,
               const int* __restrict__ x,
               float* __restrict__ out)
{
  __shared__ __align__(16) float bufA[16384];
  __shared__ __align__(16) float bufB[16384];
  __shared__ __align__(16) float sT[256];

  const int b   = blockIdx.x;
  const int tid = threadIdx.x;
  const int* xb = x + b * 36;

  if (tid == 0) bufA[0] = 1.0f;
  __syncthreads();

  float* cur = bufA;
  float* nxt = bufB;
  int S = 1;
  for (int i = 0; i < 6; ++i) {
    int wcnt = 1;
    int S3   = S;
    for (int j = 0; j < 6; ++j) {
      const int site  = i * 6 + j;
      const int spin  = xb[site];
      const int sbase = site * 512 + spin;
      const int U     = (i == 0) ? 1 : 4;
      const int V     = (U == 4) ? (S3 >> 2) : S3;
      const int code  = ((i != 0) << 3) | ((i != 5) << 2) | ((j != 0) << 1) | ((j != 5) << 0);
      switch (code) {
        case 0b0101: absorb<1,4,1,4>(tensors, sbase, cur, nxt, sT, wcnt, V, tid); break;
        case 0b0111: absorb<1,4,4,4>(tensors, sbase, cur, nxt, sT, wcnt, V, tid); break;
        case 0b0110: absorb<1,4,4,1>(tensors, sbase, cur, nxt, sT, wcnt, V, tid); break;
        case 0b1101: absorb<4,4,1,4>(tensors, sbase, cur, nxt, sT, wcnt, V, tid); break;
        case 0b1111: absorb<4,4,4,4>(tensors, sbase, cur, nxt, sT, wcnt, V, tid); break;
        case 0b1110: absorb<4,4,4,1>(tensors, sbase, cur, nxt, sT, wcnt, V, tid); break;
        case 0b1001: absorb<4,1,1,4>(tensors, sbase, cur, nxt, sT, wcnt, V, tid); break;
        case 0b1011: absorb<4,1,4,4>(tensors, sbase, cur, nxt, sT, wcnt, V, tid); break;
        case 0b1010: absorb<4,1,4,1>(tensors, sbase, cur, nxt, sT, wcnt, V, tid); break;
      }
      const int Dd = (i == 5) ? 1 : 4;
      wcnt *= Dd;
      S3 = V;
      float* t = cur; cur = nxt; nxt = t;
    }
    S = wcnt * S3;
  }
  if (tid == 0) out[b] = cur[0];
}

extern "C" void kernel_launch(void* const* d_in, const int* in_sizes, int n_in,
                              void* d_out, int out_size, void* d_ws, size_t ws_size,
                              hipStream_t stream) {
  // setup_inputs order: x (int32, BATCH*36), tensors (f32, 6*6*4*4*4*4*2)
  const int*   x       = (const int*)d_in[0];
  const float* tensors = (const float*)d_in[1];
  float*       out     = (float*)d_out;
  const int batch = in_sizes[0] / 36;
  tn_kernel<<<batch, NTH, 0, stream>>>(tensors, x, out);
}

// Round 2
// 196.335 us; speedup vs baseline: 1.5946x; 1.5946x over previous
//
#include <hip/hip_runtime.h>

#define NTH 256

// Bijective LDS word-index swizzle: XOR word bits [8:6] into bank-group bits [4:2].
// Constant over any 4-aligned float4 block -> preserves b128 contiguity.
__device__ __forceinline__ int swz(int f) { return f ^ (((f >> 6) & 7) << 2); }

__device__ __forceinline__ void fma4(float4& a, const float4& v, float s) {
  a.x = fmaf(v.x, s, a.x);
  a.y = fmaf(v.y, s, a.y);
  a.z = fmaf(v.z, s, a.z);
  a.w = fmaf(v.w, s, a.w);
}

// One absorption step, IN-PLACE on buf:
//   out[((w*D+d)*R+r)*V + v] = sum_{h,u} in[((w*H+h)*U+u)*V + v] * T[u,d,h,r]
// Compute phase accumulates all of a thread's outputs in registers, then a
// barrier, then writeback — so input and output share one LDS buffer.
// T staged in LDS as sT[hu*DR + d*R + r], read as wave-uniform broadcasts.
template<int U, int D, int H, int R>
__device__ __forceinline__ void step(const float* __restrict__ tens, int sbase,
                                     float* __restrict__ buf,
                                     float* __restrict__ sT,
                                     int wcnt, int V, int tid)
{
  constexpr int HU = H * U, DR = D * R;
  constexpr int TSZ = HU * DR;
  if (tid < TSZ) {
    int t = tid;
    int r = t % R; t /= R;
    int d = t % D; t /= D;
    int u = t % U; t /= U;
    int h = t;
    // tensors[i][j][u][d][l][r][p]: strides 512,512,128,32,8,2,1
    sT[tid] = tens[sbase + u * 128 + d * 32 + h * 8 + r * 2];
  }
  __syncthreads();

  if (V >= 4) {
    // Path A: item = (w, v-quad); thread computes all DR outputs (DR in {4,16}).
    const int Vq    = V >> 2;
    const int lvq   = 31 - __clz(Vq);
    const int items = wcnt * Vq;           // <= 256 always on this path
    const int s     = tid;
    const bool act  = s < items;
    float4 acc[DR];
    if (act) {
#pragma unroll
      for (int q = 0; q < DR; ++q) acc[q] = make_float4(0.f, 0.f, 0.f, 0.f);
      const int vb = (s & (Vq - 1)) << 2;
      const int w  = s >> lvq;
      const int ib = w * HU * V + vb;
#pragma unroll
      for (int hu = 0; hu < HU; ++hu) {
        const float4 a = *(const float4*)&buf[swz(ib + hu * V)];
#pragma unroll
        for (int q = 0; q < DR / 4; ++q) {
          const float4 t = *(const float4*)&sT[hu * DR + 4 * q];  // broadcast
          fma4(acc[4 * q + 0], a, t.x);
          fma4(acc[4 * q + 1], a, t.y);
          fma4(acc[4 * q + 2], a, t.z);
          fma4(acc[4 * q + 3], a, t.w);
        }
      }
    }
    __syncthreads();
    if (act) {
      const int vb = (s & (Vq - 1)) << 2;
      const int w  = s >> lvq;
      const int ob = w * DR * V + vb;
#pragma unroll
      for (int q = 0; q < DR; ++q)
        *(float4*)&buf[swz(ob + q * V)] = acc[q];
    }
    __syncthreads();
  } else {
    // Path B: V == 1. item = w; in contiguous over hu, out contiguous over dr.
    const int items = wcnt;
    if (DR >= 4) {
      constexpr int NQ  = DR / 4;
      constexpr int IPT = (DR == 4) ? 4 : 1;   // items <= IPT*NTH on this path
      float4 acc[IPT][NQ];
#pragma unroll
      for (int it = 0; it < IPT; ++it) {
        const int s = tid + it * NTH;
        if (s < items) {
#pragma unroll
          for (int q = 0; q < NQ; ++q) acc[it][q] = make_float4(0.f, 0.f, 0.f, 0.f);
          const int ib = s * HU;
          if (HU >= 4) {
#pragma unroll
            for (int hq = 0; hq < HU / 4; ++hq) {
              const float4 a = *(const float4*)&buf[swz(ib + 4 * hq)];
              const float av[4] = {a.x, a.y, a.z, a.w};
#pragma unroll
              for (int k = 0; k < 4; ++k) {
                const int hu = 4 * hq + k;
#pragma unroll
                for (int q = 0; q < NQ; ++q) {
                  const float4 t = *(const float4*)&sT[hu * DR + 4 * q];
                  fma4(acc[it][q], t, av[k]);
                }
              }
            }
          } else {  // HU == 1
            const float a = buf[swz(ib)];
#pragma unroll
            for (int q = 0; q < NQ; ++q) {
              const float4 t = *(const float4*)&sT[4 * q];
              fma4(acc[it][q], t, a);
            }
          }
        }
      }
      __syncthreads();
#pragma unroll
      for (int it = 0; it < IPT; ++it) {
        const int s = tid + it * NTH;
        if (s < items) {
          const int ob = s * DR;
#pragma unroll
          for (int q = 0; q < NQ; ++q)
            *(float4*)&buf[swz(ob + 4 * q)] = acc[it][q];
        }
      }
      __syncthreads();
    } else {
      // DR == 1 (final corner site; tiny)
      float acc = 0.f;
      const bool act = tid < items;
      if (act) {
        const int ib = tid * HU;
#pragma unroll
        for (int hu = 0; hu < HU; ++hu)
          acc += buf[swz(ib + hu)] * sT[hu];
      }
      __syncthreads();
      if (act) buf[swz(tid)] = acc;
      __syncthreads();
    }
  }
}

__global__ __launch_bounds__(NTH, 2)
void tn_kernel(const float* __restrict__ tensors,
               const int* __restrict__ x,
               float* __restrict__ out)
{
  __shared__ __align__(16) float buf[16384];   // 64 KB state, in-place
  __shared__ __align__(16) float sT[256];      // staged per-site T

  const int b   = blockIdx.x;
  const int tid = threadIdx.x;
  const int* xb = x + b * 36;

  if (tid == 0) buf[0] = 1.0f;   // swz(0)==0
  __syncthreads();

  int S = 1;
  for (int i = 0; i < 6; ++i) {
    int wcnt = 1;
    int S3   = S;
    for (int j = 0; j < 6; ++j) {
      const int site  = i * 6 + j;
      const int spin  = xb[site];
      const int sbase = site * 512 + spin;
      const int U     = (i == 0) ? 1 : 4;
      const int V     = (U == 4) ? (S3 >> 2) : S3;
      const int code  = ((i != 0) << 3) | ((i != 5) << 2) | ((j != 0) << 1) | ((j != 5) << 0);
      switch (code) {
        case 0b0101: step<1,4,1,4>(tensors, sbase, buf, sT, wcnt, V, tid); break;
        case 0b0111: step<1,4,4,4>(tensors, sbase, buf, sT, wcnt, V, tid); break;
        case 0b0110: step<1,4,4,1>(tensors, sbase, buf, sT, wcnt, V, tid); break;
        case 0b1101: step<4,4,1,4>(tensors, sbase, buf, sT, wcnt, V, tid); break;
        case 0b1111: step<4,4,4,4>(tensors, sbase, buf, sT, wcnt, V, tid); break;
        case 0b1110: step<4,4,4,1>(tensors, sbase, buf, sT, wcnt, V, tid); break;
        case 0b1001: step<4,1,1,4>(tensors, sbase, buf, sT, wcnt, V, tid); break;
        case 0b1011: step<4,1,4,4>(tensors, sbase, buf, sT, wcnt, V, tid); break;
        case 0b1010: step<4,1,4,1>(tensors, sbase, buf, sT, wcnt, V, tid); break;
      }
      const int Dd = (i == 5) ? 1 : 4;
      wcnt *= Dd;
      S3 = V;
    }
    S = wcnt * S3;
  }
  if (tid == 0) out[b] = buf[0];
}

extern "C" void kernel_launch(void* const* d_in, const int* in_sizes, int n_in,
                              void* d_out, int out_size, void* d_ws, size_t ws_size,
                              hipStream_t stream) {
  // setup_inputs order: x (int32, BATCH*36), tensors (f32, 6*6*4*4*4*4*2)
  const int*   x       = (const int*)d_in[0];
  const float* tensors = (const float*)d_in[1];
  float*       out     = (float*)d_out;
  const int batch = in_sizes[0] / 36;
  tn_kernel<<<batch, NTH, 0, stream>>>(tensors, x, out);
}

// Round 3
// 174.305 us; speedup vs baseline: 1.7962x; 1.1264x over previous
//
#include <hip/hip_runtime.h>

#define NTH 256

// Bijective LDS word-index swizzle: XOR word bits [8:6] into bank-group bits [4:2].
// Constant over any 4-aligned float4 block -> preserves b128 contiguity.
__device__ __forceinline__ int swz(int f) { return f ^ (((f >> 6) & 7) << 2); }

__device__ __forceinline__ void fma4(float4& a, const float4& v, float s) {
  a.x = fmaf(v.x, s, a.x);
  a.y = fmaf(v.y, s, a.y);
  a.z = fmaf(v.z, s, a.z);
  a.w = fmaf(v.w, s, a.w);
}

// ---------------------------------------------------------------------------
// Prep: repack tensors into per-(site,spin) contiguous slabs of 256 floats:
//   Tpack[(site*2+spin)*256 + ((h*U+u)*D+d)*R+r] = tens[site*512 + u*128+d*32+h*8+r*2+spin]
// 73.7 KB total -> L1/L2 resident; main kernel reads T via uniform-address
// vector loads (no LDS pipe pressure).
// ---------------------------------------------------------------------------
__global__ void prep_kernel(const float* __restrict__ tens, float* __restrict__ tp)
{
  const int site = blockIdx.x >> 1;
  const int p    = blockIdx.x & 1;
  const int i = site / 6, j = site % 6;
  const int U = (i == 0) ? 1 : 4;
  const int D = (i == 5) ? 1 : 4;
  const int H = (j == 0) ? 1 : 4;
  const int R = (j == 5) ? 1 : 4;
  const int tsz = U * D * H * R;
  const int t = threadIdx.x;
  if (t < tsz) {
    int tt = t;
    const int r = tt % R; tt /= R;
    const int d = tt % D; tt /= D;
    const int u = tt % U; tt /= U;
    const int h = tt;
    tp[(site * 2 + p) * 256 + t] =
        tens[site * 512 + u * 128 + d * 32 + h * 8 + r * 2 + p];
  }
}

// ---------------------------------------------------------------------------
// One absorption step, IN-PLACE on buf, T read from global (tb):
//   out[((w*D+d)*R+r)*V + v] = sum_{h,u} in[((w*H+h)*U+u)*V + v] * tb[hu*DR + d*R+r]
// ---------------------------------------------------------------------------
template<int U, int D, int H, int R>
__device__ __forceinline__ void step(const float* __restrict__ tb,
                                     float* __restrict__ buf,
                                     int wcnt, int V, int tid)
{
  constexpr int HU = H * U, DR = D * R;

  if (V >= 4) {
    const int Vq    = V >> 2;
    const int lvq   = 31 - __clz(Vq);
    const int items = wcnt * Vq;           // <= 256 on this path
    const bool act  = tid < items;
    float4 acc[DR];
    if (act) {
      const int vb = (tid & (Vq - 1)) << 2;
      const int w  = tid >> lvq;
      const int ib = w * HU * V + vb;
      float4 iv[HU];
#pragma unroll
      for (int hu = 0; hu < HU; ++hu)
        iv[hu] = *(const float4*)&buf[swz(ib + hu * V)];
#pragma unroll
      for (int q = 0; q < DR; ++q) acc[q] = make_float4(0.f, 0.f, 0.f, 0.f);
#pragma unroll
      for (int hu = 0; hu < HU; ++hu) {
#pragma unroll
        for (int q = 0; q < DR / 4; ++q) {
          const float4 t = *(const float4*)&tb[hu * DR + 4 * q];  // uniform, L1
          fma4(acc[4 * q + 0], iv[hu], t.x);
          fma4(acc[4 * q + 1], iv[hu], t.y);
          fma4(acc[4 * q + 2], iv[hu], t.z);
          fma4(acc[4 * q + 3], iv[hu], t.w);
        }
      }
    }
    __syncthreads();
    if (act) {
      const int vb = (tid & (Vq - 1)) << 2;
      const int w  = tid >> lvq;
      const int ob = w * DR * V + vb;
#pragma unroll
      for (int q = 0; q < DR; ++q)
        *(float4*)&buf[swz(ob + q * V)] = acc[q];
    }
    __syncthreads();
  } else {
    // V == 1 path: in contiguous over hu, out contiguous over dr.
    const int items = wcnt;
    if (DR >= 4) {
      constexpr int NQ  = DR / 4;
      constexpr int IPT = (DR == 4) ? 4 : 1;
      float4 acc[IPT][NQ];
#pragma unroll
      for (int it = 0; it < IPT; ++it) {
        const int s = tid + it * NTH;
        if (s < items) {
#pragma unroll
          for (int q = 0; q < NQ; ++q) acc[it][q] = make_float4(0.f, 0.f, 0.f, 0.f);
          const int ib = s * HU;
          if (HU >= 4) {
#pragma unroll
            for (int hq = 0; hq < HU / 4; ++hq) {
              const float4 a = *(const float4*)&buf[swz(ib + 4 * hq)];
              const float av[4] = {a.x, a.y, a.z, a.w};
#pragma unroll
              for (int k = 0; k < 4; ++k) {
                const int hu = 4 * hq + k;
#pragma unroll
                for (int q = 0; q < NQ; ++q) {
                  const float4 t = *(const float4*)&tb[hu * DR + 4 * q];
                  fma4(acc[it][q], t, av[k]);
                }
              }
            }
          } else {  // HU == 1
            const float a = buf[swz(ib)];
#pragma unroll
            for (int q = 0; q < NQ; ++q) {
              const float4 t = *(const float4*)&tb[4 * q];
              fma4(acc[it][q], t, a);
            }
          }
        }
      }
      __syncthreads();
#pragma unroll
      for (int it = 0; it < IPT; ++it) {
        const int s = tid + it * NTH;
        if (s < items) {
          const int ob = s * DR;
#pragma unroll
          for (int q = 0; q < NQ; ++q)
            *(float4*)&buf[swz(ob + 4 * q)] = acc[it][q];
        }
      }
      __syncthreads();
    } else {
      // DR == 1 (final corner site)
      float acc = 0.f;
      const bool act = tid < items;
      if (act) {
        const int ib = tid * HU;
#pragma unroll
        for (int hu = 0; hu < HU; ++hu)
          acc += buf[swz(ib + hu)] * tb[hu];
      }
      __syncthreads();
      if (act) buf[swz(tid)] = acc;
      __syncthreads();
    }
  }
}

__global__ __launch_bounds__(NTH, 2)
void tn_kernel_g(const float* __restrict__ tp,
                 const int* __restrict__ x,
                 float* __restrict__ out)
{
  __shared__ __align__(16) float buf[16384];   // 64 KB state, in-place

  const int b   = blockIdx.x;
  const int tid = threadIdx.x;
  const int* xb = x + b * 36;

  if (tid == 0) buf[0] = 1.0f;   // swz(0)==0
  __syncthreads();

  int S = 1;
  for (int i = 0; i < 6; ++i) {
    int wcnt = 1;
    int S3   = S;
    for (int j = 0; j < 6; ++j) {
      const int site = i * 6 + j;
      const int spin = xb[site];
      const float* tb = tp + (site * 2 + spin) * 256;
      const int U    = (i == 0) ? 1 : 4;
      const int V    = (U == 4) ? (S3 >> 2) : S3;
      const int code = ((i != 0) << 3) | ((i != 5) << 2) | ((j != 0) << 1) | ((j != 5) << 0);
      switch (code) {
        case 0b0101: step<1,4,1,4>(tb, buf, wcnt, V, tid); break;
        case 0b0111: step<1,4,4,4>(tb, buf, wcnt, V, tid); break;
        case 0b0110: step<1,4,4,1>(tb, buf, wcnt, V, tid); break;
        case 0b1101: step<4,4,1,4>(tb, buf, wcnt, V, tid); break;
        case 0b1111: step<4,4,4,4>(tb, buf, wcnt, V, tid); break;
        case 0b1110: step<4,4,4,1>(tb, buf, wcnt, V, tid); break;
        case 0b1001: step<4,1,1,4>(tb, buf, wcnt, V, tid); break;
        case 0b1011: step<4,1,4,4>(tb, buf, wcnt, V, tid); break;
        case 0b1010: step<4,1,4,1>(tb, buf, wcnt, V, tid); break;
      }
      const int Dd = (i == 5) ? 1 : 4;
      wcnt *= Dd;
      S3 = V;
    }
    S = wcnt * S3;
  }
  if (tid == 0) out[b] = buf[0];
}

// ---------------------------------------------------------------------------
// Fallback (ws too small): round-2 kernel, T staged in LDS.
// ---------------------------------------------------------------------------
template<int U, int D, int H, int R>
__device__ __forceinline__ void step_lds(const float* __restrict__ tens, int sbase,
                                         float* __restrict__ buf,
                                         float* __restrict__ sT,
                                         int wcnt, int V, int tid)
{
  constexpr int HU = H * U, DR = D * R;
  constexpr int TSZ = HU * DR;
  if (tid < TSZ) {
    int t = tid;
    const int r = t % R; t /= R;
    const int d = t % D; t /= D;
    const int u = t % U; t /= U;
    const int h = t;
    sT[tid] = tens[sbase + u * 128 + d * 32 + h * 8 + r * 2];
  }
  __syncthreads();
  step<U, D, H, R>(sT, buf, wcnt, V, tid);
}

__global__ __launch_bounds__(NTH, 2)
void tn_kernel_lds(const float* __restrict__ tensors,
                   const int* __restrict__ x,
                   float* __restrict__ out)
{
  __shared__ __align__(16) float buf[16384];
  __shared__ __align__(16) float sT[256];

  const int b   = blockIdx.x;
  const int tid = threadIdx.x;
  const int* xb = x + b * 36;

  if (tid == 0) buf[0] = 1.0f;
  __syncthreads();

  int S = 1;
  for (int i = 0; i < 6; ++i) {
    int wcnt = 1;
    int S3   = S;
    for (int j = 0; j < 6; ++j) {
      const int site  = i * 6 + j;
      const int spin  = xb[site];
      const int sbase = site * 512 + spin;
      const int U     = (i == 0) ? 1 : 4;
      const int V     = (U == 4) ? (S3 >> 2) : S3;
      const int code  = ((i != 0) << 3) | ((i != 5) << 2) | ((j != 0) << 1) | ((j != 5) << 0);
      switch (code) {
        case 0b0101: step_lds<1,4,1,4>(tensors, sbase, buf, sT, wcnt, V, tid); break;
        case 0b0111: step_lds<1,4,4,4>(tensors, sbase, buf, sT, wcnt, V, tid); break;
        case 0b0110: step_lds<1,4,4,1>(tensors, sbase, buf, sT, wcnt, V, tid); break;
        case 0b1101: step_lds<4,4,1,4>(tensors, sbase, buf, sT, wcnt, V, tid); break;
        case 0b1111: step_lds<4,4,4,4>(tensors, sbase, buf, sT, wcnt, V, tid); break;
        case 0b1110: step_lds<4,4,4,1>(tensors, sbase, buf, sT, wcnt, V, tid); break;
        case 0b1001: step_lds<4,1,1,4>(tensors, sbase, buf, sT, wcnt, V, tid); break;
        case 0b1011: step_lds<4,1,4,4>(tensors, sbase, buf, sT, wcnt, V, tid); break;
        case 0b1010: step_lds<4,1,4,1>(tensors, sbase, buf, sT, wcnt, V, tid); break;
      }
      const int Dd = (i == 5) ? 1 : 4;
      wcnt *= Dd;
      S3 = V;
    }
    S = wcnt * S3;
  }
  if (tid == 0) out[b] = buf[0];
}

extern "C" void kernel_launch(void* const* d_in, const int* in_sizes, int n_in,
                              void* d_out, int out_size, void* d_ws, size_t ws_size,
                              hipStream_t stream) {
  // setup_inputs order: x (int32, BATCH*36), tensors (f32, 6*6*4*4*4*4*2)
  const int*   x       = (const int*)d_in[0];
  const float* tensors = (const float*)d_in[1];
  float*       out     = (float*)d_out;
  const int batch = in_sizes[0] / 36;
  const size_t need = 36 * 2 * 256 * sizeof(float);   // 73728 B
  if (ws_size >= need && d_ws != nullptr) {
    float* tp = (float*)d_ws;
    prep_kernel<<<72, 256, 0, stream>>>(tensors, tp);
    tn_kernel_g<<<batch, NTH, 0, stream>>>(tp, x, out);
  } else {
    tn_kernel_lds<<<batch, NTH, 0, stream>>>(tensors, x, out);
  }
}

// Round 4
// 130.819 us; speedup vs baseline: 2.3933x; 1.3324x over previous
//
#include <hip/hip_runtime.h>

#define NTH 256

using f16x4 = __attribute__((ext_vector_type(4))) _Float16;
using f32x4 = __attribute__((ext_vector_type(4))) float;

// Swizzled halfword index for state element (m, k), k in [0,16).
// k-slot (k>>2) XOR'd with (m>>2)&3 -> conflict-free b64 reads/writes.
__device__ __forceinline__ int sidx(int m, int k) {
  return m * 16 + ((((k >> 2) ^ ((m >> 2) & 3)) << 2) | (k & 3));
}

// ---------------------------------------------------------------------------
// Prep: build per-(site,spin) A-fragments (T^T) in mfma_f32_16x16x16f16 lane
// order: lane l holds A[q = l&15][k = (l>>4)*4 + jj], jj=0..3, as 4 x f16.
//   A[q,k] = T[u][d][h][r] with k = u*H + h, q = d*R + r; zero-padded outside
//   (k < H*U, q < D*R).  72 pairs x 64 lanes x 8B = 36864 B in d_ws.
// ---------------------------------------------------------------------------
__global__ void prep_mfma(const float* __restrict__ tens, uint2* __restrict__ At)
{
  const int pair = blockIdx.x;
  const int site = pair >> 1, p = pair & 1;
  const int i = site / 6, j = site % 6;
  const int U = (i == 0) ? 1 : 4;
  const int D = (i == 5) ? 1 : 4;
  const int H = (j == 0) ? 1 : 4;
  const int R = (j == 5) ? 1 : 4;
  const int lane = threadIdx.x;
  const int q   = lane & 15;
  const int kgp = lane >> 4;
  f16x4 v4;
#pragma unroll
  for (int jj = 0; jj < 4; ++jj) {
    const int k = kgp * 4 + jj;
    float val = 0.f;
    if (k < H * U && q < D * R) {
      const int u = k / H, h = k % H;   // k = u*H + h
      const int d = q / R, r = q % R;   // q = d*R + r
      // tensors[i][j][u][d][l=h][r][p]: strides 512,512,128,32,8,2,1
      val = tens[site * 512 + u * 128 + d * 32 + h * 8 + r * 2 + p];
    }
    v4[jj] = (_Float16)val;
  }
  At[pair * 64 + lane] = __builtin_bit_cast(uint2, v4);
}

// ---------------------------------------------------------------------------
// Main: one block per batch element. State lives in LDS as f16 [m][k] (k=16
// always, swizzled). Per step: read B-frags (ds_read_b64), barrier,
// mfma(T^T, state) -> D^T[q, m], convert+write into next layout, barrier.
// Within-row steps (j<5): lane's 4 values (consecutive q = d*R+r, fixed m)
// land contiguous in the next layout -> one b64 write. j==5: 4x u16 scatter.
// ---------------------------------------------------------------------------
__global__ __launch_bounds__(NTH, 4)
void tn_mfma(const uint2* __restrict__ At, const int* __restrict__ x,
             float* __restrict__ out)
{
  __shared__ __align__(16) _Float16 Hs[16384];   // 32 KB state
  const int tid = threadIdx.x, b = blockIdx.x;
  const int* xb = x + b * 36;

  // zero-init (guarantees all-finite f16 everywhere; K/N zero-pads rely on it)
  uint4* Z = (uint4*)Hs;
#pragma unroll
  for (int z = 0; z < 8; ++z) Z[tid + NTH * z] = make_uint4(0, 0, 0, 0);
  if (tid == 0) Hs[0] = (_Float16)1.0f;          // initial boundary = [1]
  __syncthreads();

  const int lane = tid & 63;
  const int wv   = tid >> 6;       // wave id (4 waves)
  const int ml   = lane & 15;      // B/D column = m-local
  const int kg   = lane >> 4;      // k-group (reads) / q-group (D rows)

  int S = 1;
  for (int i = 0; i < 6; ++i) {
    int wcnt = 1, S3 = S;
    for (int j = 0; j < 6; ++j) {
      const int site = i * 6 + j;
      const int U = (i == 0) ? 1 : 4;
      const int D = (i == 5) ? 1 : 4;
      const int V = (U == 4) ? (S3 >> 2) : S3;
      const int M = wcnt * V;                    // rows of this step
      const int lgV = 31 - __clz(V);
      // consumer (next step) params for the write mapping
      int U2, V2;
      if (j < 5) { U2 = U; V2 = (U2 == 4) ? (V >> 2) : V; }
      else       { U2 = 4; V2 = wcnt; }          // next row, V2 = wcnt
      const int lgV2 = 31 - __clz(V2);
      const int ntile = (M + 15) >> 4;

      const f16x4 a =
          __builtin_bit_cast(f16x4, At[(site * 2 + xb[site]) * 64 + lane]);

      // phase 1: load this wave's B-fragments
      f16x4 bf[16];
#pragma unroll
      for (int tt = 0; tt < 16; ++tt) {
        const int t = wv + 4 * tt;
        if (t < ntile) {
          const int m = t * 16 + ml;
          bf[tt] = *(const f16x4*)&Hs[sidx(m, kg * 4)];
        }
      }
      __syncthreads();

      // phase 2: mfma + write-back in next-step layout
#pragma unroll
      for (int tt = 0; tt < 16; ++tt) {
        const int t = wv + 4 * tt;
        if (t < ntile) {
          const int m = t * 16 + ml;
          f32x4 acc = {0.f, 0.f, 0.f, 0.f};
          acc = __builtin_amdgcn_mfma_f32_16x16x16f16(a, bf[tt], acc, 0, 0, 0);
          if (site == 35) {
            if (lane == 0) out[b] = acc[0];      // D^T[q=0, m=0]
          } else if (m < M) {
            if (j < 5) {
              // q = kg*4 + delta, R==4 -> d = kg, r = delta
              if (kg < D) {
                const int d = kg;
                const int w = m >> lgV, v = m & (V - 1);
                int u2, v2;
                if (U2 == 4) { u2 = v >> lgV2; v2 = v & (V2 - 1); }
                else         { u2 = 0;         v2 = v; }
                const int m2 = (w * D + d) * V2 + v2;
                f16x4 pk = { (_Float16)acc[0], (_Float16)acc[1],
                             (_Float16)acc[2], (_Float16)acc[3] };
                *(f16x4*)&Hs[sidx(m2, u2 * 4)] = pk;   // k2 = u2*4 + delta
              }
            } else {
              // j==5 (R==1, V==1, i<5, D==4): q = d = kg*4+delta -> kg==0
              if (kg == 0) {
#pragma unroll
                for (int dd = 0; dd < 4; ++dd) {
                  const int flat = m * 4 + dd;         // w = m; flat = w*4+d
                  const int k2 = flat >> lgV2;
                  const int m2 = flat & (V2 - 1);
                  Hs[sidx(m2, k2)] = (_Float16)acc[dd];
                }
              }
            }
          }
        }
      }
      __syncthreads();

      wcnt *= D;
      S3 = V;
    }
    S = wcnt * S3;
  }
}

extern "C" void kernel_launch(void* const* d_in, const int* in_sizes, int n_in,
                              void* d_out, int out_size, void* d_ws, size_t ws_size,
                              hipStream_t stream) {
  // setup_inputs order: x (int32, BATCH*36), tensors (f32, 6*6*4*4*4*4*2)
  const int*   x       = (const int*)d_in[0];
  const float* tensors = (const float*)d_in[1];
  float*       out     = (float*)d_out;
  const int batch = in_sizes[0] / 36;
  uint2* At = (uint2*)d_ws;                      // 72*64*8 = 36864 B
  prep_mfma<<<72, 64, 0, stream>>>(tensors, At);
  tn_mfma<<<batch, NTH, 0, stream>>>(At, x, out);
}

// Round 5
// 73.384 us; speedup vs baseline: 4.2664x; 1.7827x over previous
//
#include <hip/hip_runtime.h>

#define NTH 256

using f16x4 = __attribute__((ext_vector_type(4))) _Float16;
using f32x4 = __attribute__((ext_vector_type(4))) float;

// ===========================================================================
// FUSED-PAIR PATH
// State in LDS: S[m][k], m<1024 rows, k<16, row stride 20 halfwords (40 B).
// bank = (10*row + k/2) % 32 -> conflict-free for stride-1 and stride-4 row
// patterns and kg-groups (hand-checked for all 6 step shapes).
// Row-boundary states stored packed-flat: value(u1,vr,u2) at f = u1*1024+vr*4+u2,
// addr = (f>>4)*20 + (f&15).
// ===========================================================================

// Prep: fused pair operator A-fragments for mfma_f32_16x16x16f16.
// F[q=(d1,d2,r2)][k] = sum_rj T1[u1,d1,h,rj]*T2[u2,d2,rj,r2]
// k-meaning per type: MID: k=(u2:kb, u1:kg, h:jj); START: kb=0, k=(u1:kg, u2:jj);
// ROW0: kb=0,kg=0, k=jj=h (pair0: only jj=0).
// Layout: At[((pair*4+combo)*64 + lane)*16 + frag(qb*4+kb)] as uint2 (f16x4).
__global__ void prep_fused(const float* __restrict__ tens, uint2* __restrict__ At)
{
  const int pc   = blockIdx.x;            // 0..71
  const int pair = pc >> 2, combo = pc & 3;
  const int row = pair / 3, jp = pair % 3;
  const int s1 = combo >> 1, s2 = combo & 1;
  const int site1 = row * 6 + jp * 2, site2 = site1 + 1;
  const int U  = (row == 0) ? 1 : 4;
  const int D  = (row == 5) ? 1 : 4;
  const int H1 = (jp == 0) ? 1 : 4;
  const int R2 = (jp == 2) ? 1 : 4;
  const int lane = threadIdx.x;
  const int ql = lane & 15, kgrp = lane >> 4;
  const int type = (row == 0) ? 0 : ((jp == 0) ? 1 : 2);

  for (int f = 0; f < 16; ++f) {
    const int qb = f >> 2, kb = f & 3;
    const int q = qb * 16 + ql;
    const int d1 = q >> 4, d2 = (q >> 2) & 3, r2 = q & 3;
    f16x4 v;
    for (int jj = 0; jj < 4; ++jj) {
      int u1, u2, h, valid = 1;
      if (type == 2)      { u2 = kb; u1 = kgrp; h = jj; }
      else if (type == 1) { valid = (kb == 0); u1 = kgrp; u2 = jj; h = 0; }
      else {
        valid = (kb == 0) && (kgrp == 0);
        u1 = 0; u2 = 0;
        h = (jp == 0) ? 0 : jj;
        if (jp == 0) valid = valid && (jj == 0);
      }
      float acc = 0.f;
      if (valid && d1 < D && d2 < D && r2 < R2 && u1 < U && u2 < U && h < H1) {
        for (int rj = 0; rj < 4; ++rj) {
          const float a = tens[site1 * 512 + u1 * 128 + d1 * 32 + h  * 8 + rj * 2 + s1];
          const float bb= tens[site2 * 512 + u2 * 128 + d2 * 32 + rj * 8 + r2 * 2 + s2];
          acc += a * bb;
        }
      }
      v[jj] = (_Float16)acc;
    }
    At[(pc * 64 + lane) * 16 + f] = __builtin_bit_cast(uint2, v);
  }
}

// One fused absorption step (two sites). TYPE: 0=ROW0, 1=START, 2=MID.
// WRMODE: 0=generic (extract u3 to k), 1=row-end packed-flat, 2=final scalar.
// D4: d-legs are dim 4 (rows 0..4); false for row 5.
template<int MQ, int LGVR, int LGVC, int TYPE, int WRMODE, bool D4>
__device__ __forceinline__ void fstep(const uint2* __restrict__ At, int pc,
                                      _Float16* __restrict__ S,
                                      float* __restrict__ outp,
                                      int lane, int wv)
{
  const int ml = lane & 15, kg = lane >> 4;
  constexpr int NT  = (MQ + 15) / 16;
  constexpr int NTW = (NT + 3) / 4;
  const uint2* Ap = At + (pc * 64 + lane) * 16;

  f16x4 A[16];
  if (TYPE == 2) {
#pragma unroll
    for (int f = 0; f < (D4 ? 16 : 4); ++f)
      A[f] = __builtin_bit_cast(f16x4, Ap[f]);
  } else {
#pragma unroll
    for (int qb = 0; qb < (D4 ? 4 : 1); ++qb)
      A[qb * 4] = __builtin_bit_cast(f16x4, Ap[qb * 4]);
  }

  // phase 1: gather B-fragments into registers
  f16x4 B[NTW][4];
#pragma unroll
  for (int tt = 0; tt < NTW; ++tt) {
    const int t = wv + 4 * tt;
    if (t < NT) {
      const int m = t * 16 + ml;
      if (TYPE == 2) {
        const int w = m >> LGVR, vr = m & ((1 << LGVR) - 1);
#pragma unroll
        for (int kb = 0; kb < 4; ++kb) {
          const int r0 = (((w << 2) | kb) << LGVR) | vr;
          B[tt][kb] = *(const f16x4*)&S[r0 * 20 + kg * 4];
        }
      } else if (TYPE == 1) {
        const int f0 = ((kg << LGVR) | m) << 2;
        B[tt][0] = *(const f16x4*)&S[(f0 >> 4) * 20 + (f0 & 15)];
      } else {
        B[tt][0] = *(const f16x4*)&S[m * 20 + kg * 4];
      }
    }
  }
  __syncthreads();

  // phase 2: MFMA + in-place write in the consumer's layout
#pragma unroll
  for (int tt = 0; tt < NTW; ++tt) {
    const int t = wv + 4 * tt;
    if (t < NT) {
      const int m = t * 16 + ml;
      f32x4 acc[4];
#pragma unroll
      for (int qb = 0; qb < (D4 ? 4 : 1); ++qb) {
        acc[qb] = (f32x4){0.f, 0.f, 0.f, 0.f};
        if (TYPE == 2) {
#pragma unroll
          for (int kb = 0; kb < 4; ++kb)
            acc[qb] = __builtin_amdgcn_mfma_f32_16x16x16f16(A[qb * 4 + kb],
                                                            B[tt][kb], acc[qb], 0, 0, 0);
        } else {
          acc[qb] = __builtin_amdgcn_mfma_f32_16x16x16f16(A[qb * 4],
                                                          B[tt][0], acc[qb], 0, 0, 0);
        }
      }
      if (m < MQ) {
        if (WRMODE == 2) {
          if (lane == 0) *outp = acc[0][0];
        } else if (WRMODE == 1) {
          // row-end: only r2=0 (reg 0) valid; scatter packed-flat
#pragma unroll
          for (int qb = 0; qb < 4; ++qb) {
            const int wp = (m << 4) | (qb << 2) | kg;
            const int f  = ((wp >> 10) << 10) | ((wp & 255) << 2) | ((wp >> 8) & 3);
            S[(f >> 4) * 20 + (f & 15)] = (_Float16)acc[qb][0];
          }
        } else {
          const int w2 = m >> LGVR, vr2 = m & ((1 << LGVR) - 1);
          const int u3 = vr2 >> LGVC, vc = vr2 & ((1 << LGVC) - 1);
#pragma unroll
          for (int qb = 0; qb < (D4 ? 4 : 1); ++qb) {
            const int wq = D4 ? ((w2 << 4) | (qb << 2) | kg) : w2;
            const int m2 = (wq << LGVC) | vc;
            f16x4 pk = { (_Float16)acc[qb][0], (_Float16)acc[qb][1],
                         (_Float16)acc[qb][2], (_Float16)acc[qb][3] };
            if (D4 || kg == 0)
              *(f16x4*)&S[m2 * 20 + u3 * 4] = pk;
          }
        }
      }
    }
  }
  __syncthreads();
}

__global__ __launch_bounds__(NTH, 4)
void tn_fused(const uint2* __restrict__ At, const int* __restrict__ x,
              float* __restrict__ out)
{
  __shared__ __align__(16) _Float16 S[20480];   // 1024 rows * 20, 40 KB
  const int tid = threadIdx.x, b = blockIdx.x;
  const int lane = tid & 63, wv = tid >> 6;
  const int* xb = x + b * 36;

  uint4* Z = (uint4*)S;
#pragma unroll
  for (int z = 0; z < 10; ++z) Z[tid + NTH * z] = make_uint4(0, 0, 0, 0);
  __syncthreads();
  if (tid == 0) S[0] = (_Float16)1.0f;
  __syncthreads();

  // row 0 (tiny)
  fstep<1,   0, 0, 0, 0, true >(At, (0 << 2) | (xb[0] << 1) | xb[1], S, nullptr, lane, wv);
  fstep<16,  0, 0, 0, 0, true >(At, (1 << 2) | (xb[2] << 1) | xb[3], S, nullptr, lane, wv);
  fstep<256, 0, 0, 0, 1, true >(At, (2 << 2) | (xb[4] << 1) | xb[5], S, nullptr, lane, wv);
  // rows 1..4
#pragma unroll 1
  for (int r = 1; r <= 4; ++r) {
    const int s0 = r * 6, p0 = r * 3;
    fstep<256, 8, 6, 1, 0, true >(At, ((p0 + 0) << 2) | (xb[s0 + 0] << 1) | xb[s0 + 1], S, nullptr, lane, wv);
    fstep<256, 4, 2, 2, 0, true >(At, ((p0 + 1) << 2) | (xb[s0 + 2] << 1) | xb[s0 + 3], S, nullptr, lane, wv);
    fstep<256, 0, 0, 2, 1, true >(At, ((p0 + 2) << 2) | (xb[s0 + 4] << 1) | xb[s0 + 5], S, nullptr, lane, wv);
  }
  // row 5
  fstep<256, 8, 6, 1, 0, false>(At, (15 << 2) | (xb[30] << 1) | xb[31], S, nullptr, lane, wv);
  fstep<16,  4, 2, 2, 0, false>(At, (16 << 2) | (xb[32] << 1) | xb[33], S, nullptr, lane, wv);
  fstep<1,   0, 0, 2, 2, false>(At, (17 << 2) | (xb[34] << 1) | xb[35], S, out + b, lane, wv);
}

// ===========================================================================
// FALLBACK (ws too small): R3's in-place fp32 LDS kernel (proven, 196 us).
// ===========================================================================
__device__ __forceinline__ int swz(int f) { return f ^ (((f >> 6) & 7) << 2); }
__device__ __forceinline__ void fma4(float4& a, const float4& v, float s) {
  a.x = fmaf(v.x, s, a.x); a.y = fmaf(v.y, s, a.y);
  a.z = fmaf(v.z, s, a.z); a.w = fmaf(v.w, s, a.w);
}
template<int U, int D, int H, int R>
__device__ __forceinline__ void step_f(const float* __restrict__ tb,
                                       float* __restrict__ buf,
                                       int wcnt, int V, int tid)
{
  constexpr int HU = H * U, DR = D * R;
  if (V >= 4) {
    const int Vq = V >> 2, lvq = 31 - __clz(Vq);
    const int items = wcnt * Vq;
    const bool act = tid < items;
    float4 acc[DR];
    if (act) {
      const int vb = (tid & (Vq - 1)) << 2, w = tid >> lvq;
      const int ib = w * HU * V + vb;
      float4 iv[HU];
#pragma unroll
      for (int hu = 0; hu < HU; ++hu) iv[hu] = *(const float4*)&buf[swz(ib + hu * V)];
#pragma unroll
      for (int q = 0; q < DR; ++q) acc[q] = make_float4(0.f, 0.f, 0.f, 0.f);
#pragma unroll
      for (int hu = 0; hu < HU; ++hu)
#pragma unroll
        for (int q = 0; q < DR / 4; ++q) {
          const float4 t = *(const float4*)&tb[hu * DR + 4 * q];
          fma4(acc[4 * q + 0], iv[hu], t.x); fma4(acc[4 * q + 1], iv[hu], t.y);
          fma4(acc[4 * q + 2], iv[hu], t.z); fma4(acc[4 * q + 3], iv[hu], t.w);
        }
    }
    __syncthreads();
    if (act) {
      const int vb = (tid & (Vq - 1)) << 2, w = tid >> lvq;
      const int ob = w * DR * V + vb;
#pragma unroll
      for (int q = 0; q < DR; ++q) *(float4*)&buf[swz(ob + q * V)] = acc[q];
    }
    __syncthreads();
  } else {
    const int items = wcnt;
    if (DR >= 4) {
      constexpr int NQ = DR / 4;
      constexpr int IPT = (DR == 4) ? 4 : 1;
      float4 acc[IPT][NQ];
#pragma unroll
      for (int it = 0; it < IPT; ++it) {
        const int s = tid + it * NTH;
        if (s < items) {
#pragma unroll
          for (int q = 0; q < NQ; ++q) acc[it][q] = make_float4(0.f, 0.f, 0.f, 0.f);
          const int ib = s * HU;
          if (HU >= 4) {
#pragma unroll
            for (int hq = 0; hq < HU / 4; ++hq) {
              const float4 a = *(const float4*)&buf[swz(ib + 4 * hq)];
              const float av[4] = {a.x, a.y, a.z, a.w};
#pragma unroll
              for (int k = 0; k < 4; ++k)
#pragma unroll
                for (int q = 0; q < NQ; ++q) {
                  const float4 t = *(const float4*)&tb[(4 * hq + k) * DR + 4 * q];
                  fma4(acc[it][q], t, av[k]);
                }
            }
          } else {
            const float a = buf[swz(ib)];
#pragma unroll
            for (int q = 0; q < NQ; ++q) {
              const float4 t = *(const float4*)&tb[4 * q];
              fma4(acc[it][q], t, a);
            }
          }
        }
      }
      __syncthreads();
#pragma unroll
      for (int it = 0; it < IPT; ++it) {
        const int s = tid + it * NTH;
        if (s < items) {
          const int ob = s * DR;
#pragma unroll
          for (int q = 0; q < NQ; ++q) *(float4*)&buf[swz(ob + 4 * q)] = acc[it][q];
        }
      }
      __syncthreads();
    } else {
      float acc = 0.f;
      const bool act = tid < items;
      if (act) {
        const int ib = tid * HU;
#pragma unroll
        for (int hu = 0; hu < HU; ++hu) acc += buf[swz(ib + hu)] * tb[hu];
      }
      __syncthreads();
      if (act) buf[swz(tid)] = acc;
      __syncthreads();
    }
  }
}
template<int U, int D, int H, int R>
__device__ __forceinline__ void step_lds(const float* __restrict__ tens, int sbase,
                                         float* __restrict__ buf, float* __restrict__ sT,
                                         int wcnt, int V, int tid)
{
  constexpr int TSZ = H * U * D * R;
  if (tid < TSZ) {
    int t = tid;
    const int r = t % R; t /= R;
    const int d = t % D; t /= D;
    const int u = t % U; t /= U;
    const int h = t;
    sT[tid] = tens[sbase + u * 128 + d * 32 + h * 8 + r * 2];
  }
  __syncthreads();
  step_f<U, D, H, R>(sT, buf, wcnt, V, tid);
}
__global__ __launch_bounds__(NTH, 2)
void tn_kernel_lds(const float* __restrict__ tensors, const int* __restrict__ x,
                   float* __restrict__ out)
{
  __shared__ __align__(16) float buf[16384];
  __shared__ __align__(16) float sT[256];
  const int b = blockIdx.x, tid = threadIdx.x;
  const int* xb = x + b * 36;
  if (tid == 0) buf[0] = 1.0f;
  __syncthreads();
  int S = 1;
  for (int i = 0; i < 6; ++i) {
    int wcnt = 1, S3 = S;
    for (int j = 0; j < 6; ++j) {
      const int site = i * 6 + j, spin = xb[site];
      const int sbase = site * 512 + spin;
      const int U = (i == 0) ? 1 : 4;
      const int V = (U == 4) ? (S3 >> 2) : S3;
      const int code = ((i != 0) << 3) | ((i != 5) << 2) | ((j != 0) << 1) | ((j != 5) << 0);
      switch (code) {
        case 0b0101: step_lds<1,4,1,4>(tensors, sbase, buf, sT, wcnt, V, tid); break;
        case 0b0111: step_lds<1,4,4,4>(tensors, sbase, buf, sT, wcnt, V, tid); break;
        case 0b0110: step_lds<1,4,4,1>(tensors, sbase, buf, sT, wcnt, V, tid); break;
        case 0b1101: step_lds<4,4,1,4>(tensors, sbase, buf, sT, wcnt, V, tid); break;
        case 0b1111: step_lds<4,4,4,4>(tensors, sbase, buf, sT, wcnt, V, tid); break;
        case 0b1110: step_lds<4,4,4,1>(tensors, sbase, buf, sT, wcnt, V, tid); break;
        case 0b1001: step_lds<4,1,1,4>(tensors, sbase, buf, sT, wcnt, V, tid); break;
        case 0b1011: step_lds<4,1,4,4>(tensors, sbase, buf, sT, wcnt, V, tid); break;
        case 0b1010: step_lds<4,1,4,1>(tensors, sbase, buf, sT, wcnt, V, tid); break;
      }
      const int Dd = (i == 5) ? 1 : 4;
      wcnt *= Dd;
      S3 = V;
    }
    S = wcnt * S3;
  }
  if (tid == 0) out[b] = buf[0];
}

extern "C" void kernel_launch(void* const* d_in, const int* in_sizes, int n_in,
                              void* d_out, int out_size, void* d_ws, size_t ws_size,
                              hipStream_t stream) {
  // setup_inputs order: x (int32, BATCH*36), tensors (f32, 6*6*4*4*4*4*2)
  const int*   x       = (const int*)d_in[0];
  const float* tensors = (const float*)d_in[1];
  float*       out     = (float*)d_out;
  const int batch = in_sizes[0] / 36;
  const size_t need = 72ull * 64 * 16 * 8;   // 589824 B
  if (ws_size >= need && d_ws != nullptr) {
    uint2* At = (uint2*)d_ws;
    prep_fused<<<72, 64, 0, stream>>>(tensors, At);
    tn_fused<<<batch, NTH, 0, stream>>>(At, x, out);
  } else {
    tn_kernel_lds<<<batch, NTH, 0, stream>>>(tensors, x, out);
  }
}